// Round 1
// 103.805 us; speedup vs baseline: 1.0461x; 1.0461x over previous
//
#include <hip/hip_runtime.h>

#define C2 2.8853900817779268f  // 2*log2(e)
#define DIN 1024
#define HD 512

typedef short short8 __attribute__((ext_vector_type(8)));   // 8 bf16 (4 VGPRs)
typedef float floatx4 __attribute__((ext_vector_type(4)));  // MFMA acc

__device__ __forceinline__ float rcp_fast(float x){ return __builtin_amdgcn_rcpf(x); }
__device__ __forceinline__ float exp2_fast(float x){ return __builtin_amdgcn_exp2f(x); }
__device__ __forceinline__ float comp4(const float4& v, int i){
    return i==0 ? v.x : i==1 ? v.y : i==2 ? v.z : v.w;  // i compile-time under unroll
}
__device__ __forceinline__ unsigned short f2bf(float f){   // RNE fp32->bf16
    union{float f; unsigned int u;} v; v.f = f;
    unsigned int u = v.u;
    return (unsigned short)((u + 0x7FFFu + ((u >> 16) & 1u)) >> 16);
}

// ---------- convert: x, Wh, Wm (fp32) -> bf16 buffers ----------
__global__ __launch_bounds__(256) void convert_kernel(
    const float* __restrict__ x, const float* __restrict__ Wh,
    const float* __restrict__ Wm, unsigned short* __restrict__ xb,
    unsigned short* __restrict__ whb, unsigned short* __restrict__ wmb)
{
    int r = blockIdx.z;
    const float* s = r == 0 ? x : r == 1 ? Wh : Wm;
    unsigned short* d = r == 0 ? xb : r == 1 ? whb : wmb;
    int i = (blockIdx.x * 256 + threadIdx.x) * 4;   // 512 blocks x 256 thr x 4 = 524288
    float4 v = *(const float4*)(s + i);
    ushort4 o = { f2bf(v.x), f2bf(v.y), f2bf(v.z), f2bf(v.w) };
    *(ushort4*)(d + i) = o;
}

// ---------- MFMA gemm + fused exp2 epilogue ----------
// C[s,j] = sum_k x[s,k] * W[j,k];  E = exp2(C2*(C+bias[j]))
// mat=0 -> EH[s][j] (row-major, scores reads rows of h)
// mat=1 -> EMT[j][s] (TRANSPOSED, so scores' Ms staging is conflict-free row copies)
// One 16x16 C tile per wave via mfma_f32_16x16x32_bf16, K=1024 in 32-steps.
// C/D: col=lane&15, row=quad*4+reg  [m89/m120-verified layouts]
__global__ __launch_bounds__(256) void mfma_gemm_kernel(
    const unsigned short* __restrict__ xb, const unsigned short* __restrict__ whb,
    const unsigned short* __restrict__ wmb, const float* __restrict__ bh,
    const float* __restrict__ bm, float* __restrict__ EH, float* __restrict__ EMT)
{
    int mat = blockIdx.z;
    const unsigned short* B = mat ? wmb : whb;
    const float* bias = mat ? bm : bh;
    int j0 = blockIdx.x * 32, s0 = blockIdx.y * 32;
    int wave = threadIdx.x >> 6, lane = threadIdx.x & 63;
    int sw = (wave & 1) * 16, jw = (wave >> 1) * 16;
    int m = lane & 15, quad = lane >> 4;

    const unsigned short* ap = xb + (size_t)(s0 + sw + m) * DIN + quad * 8;
    const unsigned short* bp = B  + (size_t)(j0 + jw + m) * DIN + quad * 8;

    floatx4 acc = {0.f, 0.f, 0.f, 0.f};
    #pragma unroll 8
    for (int k = 0; k < DIN; k += 32){
        short8 af = *(const short8*)(ap + k);
        short8 bf = *(const short8*)(bp + k);
        acc = __builtin_amdgcn_mfma_f32_16x16x32_bf16(af, bf, acc, 0, 0, 0);
    }
    int col = j0 + jw + m;
    float bv = bias[col];
    if (mat == 0){
        #pragma unroll
        for (int i = 0; i < 4; i++){
            int row = s0 + sw + quad * 4 + i;
            EH[(size_t)row * HD + col] = exp2_fast(C2 * (acc[i] + bv));
        }
    } else {
        // EMT[d=col][m-rows]: quads 0..3 of a given m-lane cover one 64B line
        float4 v = { exp2_fast(C2 * (acc[0] + bv)), exp2_fast(C2 * (acc[1] + bv)),
                     exp2_fast(C2 * (acc[2] + bv)), exp2_fast(C2 * (acc[3] + bv)) };
        *(float4*)&EMT[(size_t)col * 512 + s0 + sw + quad * 4] = v;
    }
}

// ---------- scores partial: Q[ds][h][m] = sum_{d in slice} (-2 w2[d]) * rcp(1+EH[h,d]*EM[m,d])
// 32h x 64m x 64d blocks (1024 blocks, 4/CU), 256 thr, 2x4 micro.
// Hs row-major [h][d] stride 68; Ms [d][m] stride 68 (filled from EMT rows, b128, conflict-free).
// 4-term reciprocal pairing: sum_i w_i/den_i = N/D, D = prod(den), one v_rcp per 4 d-elems.
__global__ __launch_bounds__(256, 4) void scores_kernel(
    const float* __restrict__ EH, const float* __restrict__ EMT,
    const float* __restrict__ w2, float* __restrict__ Q)
{
    int m0 = blockIdx.x * 64, h0 = blockIdx.y * 32, d0 = blockIdx.z * 64;
    __shared__ float Hs[32 * 68];
    __shared__ float Ms[64 * 68];
    __shared__ float wsS[64];
    int tid = threadIdx.x;
    int tx = tid & 15, ty = tid >> 4;   // tx: m-group (x4), ty: h-group (x2)
    #pragma unroll
    for (int l = 0; l < 2; l++){        // Hs: 32 rows x 16 float4
        int slot = tid + 256 * l;
        int row = slot >> 4, q = slot & 15;
        *(float4*)&Hs[row * 68 + q * 4] =
            *(const float4*)(EH + (size_t)(h0 + row) * HD + d0 + q * 4);
    }
    #pragma unroll
    for (int l = 0; l < 4; l++){        // Ms: 64 d-rows x 16 float4, straight copy from EMT
        int slot = tid + 256 * l;
        int dd = slot >> 4, q = slot & 15;
        *(float4*)&Ms[dd * 68 + q * 4] =
            *(const float4*)(EMT + (size_t)(d0 + dd) * 512 + m0 + q * 4);
    }
    if (tid < 16){
        float4 w = *(const float4*)(w2 + d0 + tid * 4);
        float4 ws = {-2.f * w.x, -2.f * w.y, -2.f * w.z, -2.f * w.w};
        *(float4*)&wsS[tid * 4] = ws;
    }
    __syncthreads();

    float acc[2][4] = {};
    #pragma unroll 2
    for (int it = 0; it < 16; it++){
        int dk = it * 4;
        float4 w4  = *(const float4*)&wsS[dk];
        float4 hA  = *(const float4*)&Hs[(ty*2 + 0) * 68 + dk];
        float4 hB  = *(const float4*)&Hs[(ty*2 + 1) * 68 + dk];
        float4 mv0 = *(const float4*)&Ms[(dk + 0) * 68 + tx * 4];
        float4 mv1 = *(const float4*)&Ms[(dk + 1) * 68 + tx * 4];
        float4 mv2 = *(const float4*)&Ms[(dk + 2) * 68 + tx * 4];
        float4 mv3 = *(const float4*)&Ms[(dk + 3) * 68 + tx * 4];
        #pragma unroll
        for (int hh = 0; hh < 2; hh++){
            float4 hv = hh ? hB : hA;
            #pragma unroll
            for (int j = 0; j < 4; j++){
                float den0 = fmaf(hv.x, comp4(mv0, j), 1.f);
                float den1 = fmaf(hv.y, comp4(mv1, j), 1.f);
                float den2 = fmaf(hv.z, comp4(mv2, j), 1.f);
                float den3 = fmaf(hv.w, comp4(mv3, j), 1.f);
                float p01 = den0 * den1;
                float p23 = den2 * den3;
                float t1 = fmaf(w4.y, den0, w4.x * den1);   // w0*den1 + w1*den0
                float t2 = fmaf(w4.w, den2, w4.z * den3);   // w2*den3 + w3*den2
                float N  = fmaf(t2, p01, t1 * p23);
                acc[hh][j] = fmaf(N, rcp_fast(p01 * p23), acc[hh][j]);
            }
        }
    }
    float* Qp = Q + (size_t)blockIdx.z * 262144;
    #pragma unroll
    for (int i = 0; i < 2; i++){
        float4 v = {acc[i][0], acc[i][1], acc[i][2], acc[i][3]};
        *(float4*)&Qp[(h0 + ty*2 + i) * 512 + m0 + tx * 4] = v;
    }
}

// ---------- combine: out = c0 + sum of 8 d-slice partials, c0 = b2 + sum(w2)
__global__ __launch_bounds__(256) void combine_kernel(
    const float* __restrict__ Q, const float* __restrict__ w2,
    const float* __restrict__ b2, float* __restrict__ out)
{
    int tid = threadIdx.x;
    __shared__ float red[4];
    __shared__ float c0s;
    float s = 0.f;
    if (tid < 128){ float4 v = ((const float4*)w2)[tid]; s = v.x + v.y + v.z + v.w; }
    #pragma unroll
    for (int off = 32; off; off >>= 1) s += __shfl_down(s, off, 64);
    if (tid < 128 && (tid & 63) == 0) red[tid >> 6] = s;
    __syncthreads();
    if (tid == 0) c0s = red[0] + red[1] + b2[0];
    __syncthreads();
    float c0 = c0s;
    int g = blockIdx.x * 256 + tid;
    const float4* Q4 = (const float4*)Q;
    float4 a = Q4[g];
    #pragma unroll
    for (int sl = 1; sl < 8; sl++){
        float4 b = Q4[sl * 65536 + g];
        a.x += b.x; a.y += b.y; a.z += b.z; a.w += b.w;
    }
    float4 o = {a.x + c0, a.y + c0, a.z + c0, a.w + c0};
    ((float4*)out)[g] = o;
}

extern "C" void kernel_launch(void* const* d_in, const int* in_sizes, int n_in,
                              void* d_out, int out_size, void* d_ws, size_t ws_size,
                              hipStream_t stream) {
    const float* x   = (const float*)d_in[0];   // [1,512,1024]
    const float* Wh  = (const float*)d_in[1];   // [512,1024]
    const float* bh  = (const float*)d_in[2];   // [512]
    const float* Wm  = (const float*)d_in[3];   // [512,1024]
    const float* bm  = (const float*)d_in[4];   // [512]
    const float* w2  = (const float*)d_in[5];   // [512]
    const float* b2  = (const float*)d_in[6];   // [1]
    float* out = (float*)d_out;                 // [512,512]
    (void)in_sizes; (void)n_in; (void)out_size; (void)ws_size;

    float* w = (float*)d_ws;
    unsigned short* xb  = (unsigned short*)(w);            // 524288 bf16 = 262144 f
    unsigned short* whb = (unsigned short*)(w + 262144);   // 262144 f
    unsigned short* wmb = (unsigned short*)(w + 524288);   // 262144 f
    float* EH  = w + 786432;                               // 262144
    float* EMT = w + 1048576;                              // 262144 (transposed [d][m])
    float* Q   = w + 1310720;                              // 8 * 262144

    convert_kernel<<<dim3(512, 1, 3), 256, 0, stream>>>(x, Wh, Wm, xb, whb, wmb);
    mfma_gemm_kernel<<<dim3(16, 16, 2), 256, 0, stream>>>(xb, whb, wmb, bh, bm, EH, EMT);
    scores_kernel<<<dim3(8, 16, 8), 256, 0, stream>>>(EH, EMT, w2, Q);
    combine_kernel<<<256, 256, 0, stream>>>(Q, w2, b2, out);
}